// Round 4
// baseline (492.714 us; speedup 1.0000x reference)
//
#include <hip/hip_runtime.h>
#include <cstdint>
#include <cstddef>

// ---------------------------------------------------------------------------
// DatastoreReaderLayer: S=256 B=4 D=512 N=32768, TEMP=0.5
//   Wqk = Wq^T@Wk; Q2f8 = fp8(16 * 2s * (q@Wqk + bq@Wk))   [s=D^-0.5]
//   (per-q constant cq cancels in softmax -> dropped)
//   E = exp((Q2f8 . K_fp8)/16); part[chunk] = E@V (bf16), lacc = rowsum(E)
//   racc = sum_chunk part; attn = (racc/l)@Wv^T + bv
//   sdot = relu([attn|prev]@Wg1^T+bg1).wg2 ; out = attn*sg + prev*(1-sg)
// fp8 numerics: sqrt(sum w^2) ~ 0.009 -> e4m3 noise on logits/E/V perturbs
// attn by ~1e-3, far below bf16 floor (0.0156) and threshold (0.067).
// ---------------------------------------------------------------------------

typedef unsigned short u16;
typedef unsigned char u8;
typedef u8     u8x8  __attribute__((ext_vector_type(8)));
typedef u8     u8x16 __attribute__((ext_vector_type(16)));
typedef u16    u16x4 __attribute__((ext_vector_type(4)));
typedef __bf16 bf16x8 __attribute__((ext_vector_type(8)));
typedef float  f32x4 __attribute__((ext_vector_type(4)));

#define MFMA16(a, b, c) __builtin_amdgcn_mfma_f32_16x16x32_bf16( \
    __builtin_bit_cast(bf16x8, (a)), __builtin_bit_cast(bf16x8, (b)), (c), 0, 0, 0)
#define MFMA8(a, b, c) \
    __builtin_amdgcn_mfma_f32_16x16x32_fp8_fp8((long)(a), (long)(b), (c), 0, 0, 0)

__device__ __forceinline__ u16 f2bf(float f) {  // RNE float->bf16
  unsigned u = __builtin_bit_cast(unsigned, f);
  u += 0x7fffu + ((u >> 16) & 1u);
  return (u16)(u >> 16);
}
__device__ __forceinline__ float bf2f(u16 h) {
  unsigned u = ((unsigned)h) << 16;
  return __builtin_bit_cast(float, u);
}
__device__ __forceinline__ u8 f2fp8(float x) {
  return (u8)(__builtin_amdgcn_cvt_pk_fp8_f32(x, x, 0, false) & 0xff);
}
__device__ __forceinline__ int pk4(float4 v) {
  int r = __builtin_amdgcn_cvt_pk_fp8_f32(v.x, v.y, 0, false);
  return __builtin_amdgcn_cvt_pk_fp8_f32(v.z, v.w, r, true);
}

typedef u16 u16x8 __attribute__((ext_vector_type(8)));

// --------------- MFMA GEMM core, 64x64 tiles (bf16 compute) -----------------
template <bool TRANSA, bool TRANSB, bool CONCAT, bool RELU, bool OUTFP8,
          bool ROWSCALE, bool GATE, int KK>
__device__ void gemm_core(u16* As, u16* Bs, const float* __restrict__ A,
                          const float* __restrict__ A2,
                          const float* __restrict__ B,
                          const float* __restrict__ bias,
                          const float* __restrict__ lvec,
                          const float* __restrict__ wg2, float alpha,
                          void* __restrict__ Cv, float* __restrict__ sdot,
                          int bxx, int byy) {
  const int tid = threadIdx.x;
  const int w = tid >> 6, lane = tid & 63, quad = lane >> 4, l15 = lane & 15;
  const int m0 = byy * 64, n0 = bxx * 64;
  const int arow = tid >> 2, ac4 = tid & 3;
  float rs = 1.0f;
  if (ROWSCALE) rs = 1.0f / lvec[m0 + arow];
  const f32x4 fzero = {0.f, 0.f, 0.f, 0.f};
  f32x4 acc[4];
#pragma unroll
  for (int i = 0; i < 4; i++) acc[i] = fzero;

  float4 ra[4], rb[4];
  auto loadA = [&](int k0) {
    const float* src;
    if (TRANSA)
      src = A + (size_t)(k0 + arow) * 512 + m0;
    else if (CONCAT)
      src = (k0 < 512) ? (A + (size_t)(m0 + arow) * 512 + k0)
                       : (A2 + (size_t)(m0 + arow) * 512 + (k0 - 512));
    else
      src = A + (size_t)(m0 + arow) * KK + k0;
#pragma unroll
    for (int i = 0; i < 4; i++) ra[i] = *(const float4*)(src + (ac4 + 4 * i) * 4);
  };
  auto loadB = [&](int k0) {
    const float* src = TRANSB ? (B + (size_t)(n0 + arow) * KK + k0)
                              : (B + (size_t)(k0 + arow) * 512 + n0);
#pragma unroll
    for (int i = 0; i < 4; i++) rb[i] = *(const float4*)(src + (ac4 + 4 * i) * 4);
  };

  loadA(0);
  loadB(0);
#pragma unroll
  for (int k0 = 0; k0 < KK; k0 += 64) {
    __syncthreads();
#pragma unroll
    for (int i = 0; i < 4; i++) {
      int col = (ac4 + 4 * i) * 4;
      float4 x = ra[i];
      if (ROWSCALE) { x.x *= rs; x.y *= rs; x.z *= rs; x.w *= rs; }
      if (TRANSA) {
        As[(col + 0) * 72 + arow] = f2bf(x.x);
        As[(col + 1) * 72 + arow] = f2bf(x.y);
        As[(col + 2) * 72 + arow] = f2bf(x.z);
        As[(col + 3) * 72 + arow] = f2bf(x.w);
      } else {
        u16x4 oa = {f2bf(x.x), f2bf(x.y), f2bf(x.z), f2bf(x.w)};
        *(u16x4*)&As[arow * 72 + col] = oa;
      }
      float4 y = rb[i];
      if (TRANSB) {
        u16x4 ob = {f2bf(y.x), f2bf(y.y), f2bf(y.z), f2bf(y.w)};
        *(u16x4*)&Bs[arow * 72 + col] = ob;
      } else {
        Bs[(col + 0) * 72 + arow] = f2bf(y.x);
        Bs[(col + 1) * 72 + arow] = f2bf(y.y);
        Bs[(col + 2) * 72 + arow] = f2bf(y.z);
        Bs[(col + 3) * 72 + arow] = f2bf(y.w);
      }
    }
    if (k0 + 64 < KK) { loadA(k0 + 64); loadB(k0 + 64); }
    __syncthreads();
#pragma unroll
    for (int ks = 0; ks < 2; ks++) {
      u16x8 af = *(const u16x8*)&As[(w * 16 + l15) * 72 + ks * 32 + quad * 8];
#pragma unroll
      for (int nt = 0; nt < 4; nt++) {
        u16x8 bf = *(const u16x8*)&Bs[(nt * 16 + l15) * 72 + ks * 32 + quad * 8];
        acc[nt] = MFMA16(af, bf, acc[nt]);
      }
    }
  }

  if (GATE) {
    float part[4] = {0.f, 0.f, 0.f, 0.f};
#pragma unroll
    for (int nt = 0; nt < 4; nt++) {
      int col = n0 + nt * 16 + l15;
      float b = bias[col], wv = wg2[col];
#pragma unroll
      for (int i = 0; i < 4; i++) part[i] += fmaxf((acc[nt][i] + b) * alpha, 0.f) * wv;
    }
#pragma unroll
    for (int i = 0; i < 4; i++) {
      float v = part[i];
      v += __shfl_xor(v, 1, 64); v += __shfl_xor(v, 2, 64);
      v += __shfl_xor(v, 4, 64); v += __shfl_xor(v, 8, 64);
      if (l15 == 0) atomicAdd(&sdot[m0 + w * 16 + quad * 4 + i], v);
    }
  } else {
#pragma unroll
    for (int nt = 0; nt < 4; nt++) {
      int col = n0 + nt * 16 + l15;
      float b = bias ? bias[col] : 0.f;
#pragma unroll
      for (int i = 0; i < 4; i++) {
        int row = m0 + w * 16 + quad * 4 + i;
        float y = (acc[nt][i] + b) * alpha;
        if (RELU) y = fmaxf(y, 0.f);
        if (OUTFP8)
          ((u8*)Cv)[(size_t)row * 512 + col] = f2fp8(y);
        else
          ((float*)Cv)[(size_t)row * 512 + col] = y;
      }
    }
  }
}

template <bool TRANSA, bool TRANSB, bool CONCAT, bool RELU, bool OUTFP8,
          bool ROWSCALE, bool GATE, int KK>
__global__ __launch_bounds__(256, 2) void gemm64(
    const float* __restrict__ A, const float* __restrict__ A2,
    const float* __restrict__ B, const float* __restrict__ bias,
    const float* __restrict__ lvec, const float* __restrict__ wg2, float alpha,
    void* __restrict__ Cv, float* __restrict__ sdot) {
  __shared__ u16 As[64 * 72];
  __shared__ u16 Bs[64 * 72];
  gemm_core<TRANSA, TRANSB, CONCAT, RELU, OUTFP8, ROWSCALE, GATE, KK>(
      As, Bs, A, A2, B, bias, lvec, wg2, alpha, Cv, sdot, blockIdx.x,
      blockIdx.y);
}

// ------- prep_all: kf8 cvt + vtf8 transpose + Wqk gemm + b2pre + zeros ------
__global__ __launch_bounds__(256) void prep_all(
    const float* __restrict__ dk, const float* __restrict__ dv,
    const float* __restrict__ Wq, const float* __restrict__ Wk,
    const float* __restrict__ bq, u8* __restrict__ kf8, u8* __restrict__ vtf8,
    float* __restrict__ Wqk, float* __restrict__ b2pre,
    float* __restrict__ zvec) {
  __shared__ __align__(16) char smem[18432];
  const int bx = blockIdx.x, t = threadIdx.x;
  if (bx < 4096) {  // dstore_v -> fp8 transposed [512][32768]
    u8* Lt = (u8*)smem;  // [64 d][72]
    const int n0 = (bx & 511) * 64, d0 = (bx >> 9) * 64;
    const int n = t >> 2, c4 = t & 3;
#pragma unroll
    for (int i = 0; i < 4; i++) {
      int col = (c4 + 4 * i) * 4;
      float4 x = *(const float4*)(dv + (size_t)(n0 + n) * 512 + d0 + col);
      Lt[(col + 0) * 72 + n] = f2fp8(x.x);
      Lt[(col + 1) * 72 + n] = f2fp8(x.y);
      Lt[(col + 2) * 72 + n] = f2fp8(x.z);
      Lt[(col + 3) * 72 + n] = f2fp8(x.w);
    }
    __syncthreads();
#pragma unroll
    for (int u = 0; u < 2; u++) {
      int unit = t + 256 * u;  // 512 units: 64 d x 8 chunks of 8 bytes
      int d = unit >> 3, un = unit & 7;
      *(u8x8*)(vtf8 + (size_t)(d0 + d) * 32768 + n0 + un * 8) =
          *(const u8x8*)&Lt[d * 72 + un * 8];
    }
  } else if (bx < 8192) {  // dstore_k -> fp8
    const int j = bx - 4096;
    size_t i0 = ((size_t)j * 256 + t) * 16;
    const float* s = dk + i0;
    int4 o;
    o.x = pk4(*(const float4*)(s + 0));
    o.y = pk4(*(const float4*)(s + 4));
    o.z = pk4(*(const float4*)(s + 8));
    o.w = pk4(*(const float4*)(s + 12));
    *(int4*)(kf8 + i0) = o;
  } else if (bx < 8256) {  // Wqk = Wq^T @ Wk (64 blocks, 8x8 tiles)
    const int id = bx - 8192;
    gemm_core<true, false, false, false, false, false, false, 512>(
        (u16*)smem, (u16*)(smem + 9216), Wq, nullptr, Wk, nullptr, nullptr,
        nullptr, 1.0f, Wqk, nullptr, id & 7, id >> 3);
  } else if (bx < 8264) {  // b2pre = bq @ Wk
    float* rb = (float*)smem;
    int c = (bx - 8256) * 64 + (t & 63), seg = t >> 6;
    float s = 0.f;
    for (int k = seg * 128; k < seg * 128 + 128; k++)
      s += bq[k] * Wk[(size_t)k * 512 + c];
    rb[t] = s;
    __syncthreads();
    if (t < 64) b2pre[c] = rb[t] + rb[t + 64] + rb[t + 128] + rb[t + 192];
  } else {  // zero lacc + sdot (contiguous 2048 floats)
    for (int i = t; i < 2048; i += 256) zvec[i] = 0.f;
  }
}

// ------------------------------- flash kernel -------------------------------
// grid 512: xcd=bx&7, qt=(bx>>3)&15, chunk=xcd*4+(bx>>7); 1024 rows/chunk,
// 16 subtiles x 64n. 8 waves (512 thr), fp8 operands, ~41KB LDS, <=128 VGPR
// -> 2 blocks/CU (two independent barrier domains; cross-block phase overlap).
// logits: A=Q(LDS, 16B-XOR swizzle), B=K(global); PV: A=V(global), B=E(LDS).
// ONE barrier/subtile (Es double-buffered; logits never reads Es).
__global__ __launch_bounds__(512, 4) void flash(
    const u8* __restrict__ kf8,   // [32768][512] fp8
    const u8* __restrict__ vtf8,  // [512][32768] fp8 (V transposed)
    const u8* __restrict__ q2f8,  // [1024][512] fp8 (16x scaled)
    u16* __restrict__ part,       // [1024][32][512] bf16 partials
    float* __restrict__ lacc) {   // [1024] fp32, pre-zeroed
  __shared__ u8 Qs[64 * 512];
  __shared__ u8 Es[2][64 * 64];
  const int tid = threadIdx.x;
  const int w = tid >> 6, lane = tid & 63, quad = lane >> 4, l15 = lane & 15;
  const int bx = blockIdx.x;
  const int qt = (bx >> 3) & 15;
  const int chunk = (bx & 7) * 4 + (bx >> 7);
  const int rowbase = chunk * 1024;
  const int qbase = qt * 64;
  const int qh = w & 1, ng = w >> 1;  // q-half (32q), n-group (16n of 64)

  {  // Q tile -> LDS, 16B chunks XOR-swizzled by (row&7): conflict-free b64
    const int row = tid >> 3, cb = tid & 7;
    const u8* src = q2f8 + (size_t)(qbase + row) * 512 + cb * 64;
#pragma unroll
    for (int i = 0; i < 4; i++) {
      int c2 = cb * 4 + i;
      *(u8x16*)&Qs[row * 512 + ((c2 ^ (row & 7)) << 4)] =
          *(const u8x16*)(src + i * 16);
    }
  }
  const f32x4 fzero = {0.f, 0.f, 0.f, 0.f};
  f32x4 acc[4][4];
#pragma unroll
  for (int a = 0; a < 4; a++)
#pragma unroll
    for (int b = 0; b < 4; b++) acc[a][b] = fzero;
  float lp[8] = {0.f, 0.f, 0.f, 0.f, 0.f, 0.f, 0.f, 0.f};
  __syncthreads();

  const int q7 = l15 & 7;
  const int qrow0 = (qh * 32 + l15) * 512;
  const int qh2 = quad >> 1, hb = (quad & 1) * 8;

#pragma unroll 1
  for (int sub = 0; sub < 16; ++sub) {
    const int n0 = rowbase + sub * 64;
    // K fragments (L2-hot global)
    long kf[16];
    const u8* kp = kf8 + (size_t)(n0 + ng * 16 + l15) * 512 + quad * 8;
#pragma unroll
    for (int ks = 0; ks < 16; ks++) kf[ks] = *(const long*)(kp + ks * 32);
    // logits: A = Q (LDS swizzled), B = K; C: row=q(quad*4+i), col=n(l15)
    f32x4 sa0 = fzero, sa1 = fzero;
#pragma unroll
    for (int ks = 0; ks < 16; ks++) {
      int cidx = (((ks * 2 + qh2) ^ q7) << 4) + hb;
      long a0 = *(const long*)&Qs[qrow0 + cidx];
      long a1 = *(const long*)&Qs[qrow0 + 16 * 512 + cidx];
      sa0 = MFMA8(a0, kf[ks], sa0);
      sa1 = MFMA8(a1, kf[ks], sa1);
    }
    // exp + fp8 E store (byte scatter into swizzled Es) + l partials
    u8* ew = Es[sub & 1];
    const int n = ng * 16 + l15;
#pragma unroll
    for (int qa = 0; qa < 2; qa++) {
      f32x4 sv = qa ? sa1 : sa0;
      float e0 = __expf(sv[0] * 0.0625f);
      float e1 = __expf(sv[1] * 0.0625f);
      float e2 = __expf(sv[2] * 0.0625f);
      float e3 = __expf(sv[3] * 0.0625f);
      lp[qa * 4 + 0] += e0; lp[qa * 4 + 1] += e1;
      lp[qa * 4 + 2] += e2; lp[qa * 4 + 3] += e3;
      int pk = __builtin_amdgcn_cvt_pk_fp8_f32(e0, e1, 0, false);
      pk = __builtin_amdgcn_cvt_pk_fp8_f32(e2, e3, pk, true);
#pragma unroll
      for (int i = 0; i < 4; i++) {
        int q = qh * 32 + qa * 16 + quad * 4 + i;
        ew[q * 64 + ((((n >> 3) ^ (q & 7))) << 3) + (n & 7)] =
            (u8)(pk >> (8 * i));
      }
    }
    // V fragments (issued before barrier; drained by its waitcnt)
    long vf[4][2];
#pragma unroll
    for (int dt = 0; dt < 4; dt++)
#pragma unroll
      for (int nk = 0; nk < 2; nk++)
        vf[dt][nk] = *(const long*)(vtf8 +
                                    (size_t)(w * 64 + dt * 16 + l15) * 32768 +
                                    n0 + nk * 32 + quad * 8);
    __syncthreads();
    // PV: A = V, B = E; C: row=d(quad*4+i), col=q(l15)
    const u8* er = Es[sub & 1];
#pragma unroll
    for (int nk = 0; nk < 2; nk++) {
      long ef[4];
#pragma unroll
      for (int qt4 = 0; qt4 < 4; qt4++) {
        int q = qt4 * 16 + l15;
        ef[qt4] = *(const long*)&er[q * 64 + ((((nk * 4 + quad) ^ (q & 7))) << 3)];
      }
#pragma unroll
      for (int dt = 0; dt < 4; dt++)
#pragma unroll
        for (int qt4 = 0; qt4 < 4; qt4++)
          acc[dt][qt4] = MFMA8(vf[dt][nk], ef[qt4], acc[dt][qt4]);
    }
  }
  // epilogue: bf16 partial store (no atomics) + lacc atomics
#pragma unroll
  for (int qt4 = 0; qt4 < 4; qt4++) {
    int qq = qbase + qt4 * 16 + l15;
#pragma unroll
    for (int dt = 0; dt < 4; dt++) {
      u16x4 o = {f2bf(acc[dt][qt4][0]), f2bf(acc[dt][qt4][1]),
                 f2bf(acc[dt][qt4][2]), f2bf(acc[dt][qt4][3])};
      *(u16x4*)(part + ((size_t)qq * 32 + chunk) * 512 + w * 64 + dt * 16 +
                quad * 4) = o;
    }
  }
#pragma unroll
  for (int j = 0; j < 8; j++) {
    float v = lp[j];
    v += __shfl_xor(v, 1, 64); v += __shfl_xor(v, 2, 64);
    v += __shfl_xor(v, 4, 64); v += __shfl_xor(v, 8, 64);
    lp[j] = v;
  }
  if (l15 == 0) {
#pragma unroll
    for (int qa = 0; qa < 2; qa++)
#pragma unroll
      for (int i = 0; i < 4; i++)
        atomicAdd(&lacc[qbase + qh * 32 + qa * 16 + quad * 4 + i],
                  lp[qa * 4 + i]);
  }
}

// ------------------- reduce: racc[q][d] = sum_c part[q][c][d] ---------------
__global__ __launch_bounds__(256) void reduce_racc(const u16* __restrict__ part,
                                                   float* __restrict__ racc) {
  const int q = blockIdx.x, t = threadIdx.x;
  const u16* p = part + (size_t)q * 32 * 512 + t * 2;
  float s0 = 0.f, s1 = 0.f;
#pragma unroll
  for (int c = 0; c < 32; c++) {
    unsigned v = *(const unsigned*)(p + c * 512);
    s0 += bf2f((u16)(v & 0xffff));
    s1 += bf2f((u16)(v >> 16));
  }
  float2 o = {s0, s1};
  *(float2*)(racc + (size_t)q * 512 + t * 2) = o;
}

// ----------------------- finalize: sigma gate + mix -------------------------
__global__ __launch_bounds__(128) void finalize(
    const float* __restrict__ sdot, const float* __restrict__ bg2,
    const float* __restrict__ attn, const float* __restrict__ prev,
    float* __restrict__ out) {
  int r = blockIdx.x, t = threadIdx.x;
  float sg = 1.f / (1.f + __expf(-(sdot[r] + bg2[0])));
  float4 a = ((const float4*)(attn + (size_t)r * 512))[t];
  float4 p = ((const float4*)(prev + (size_t)r * 512))[t];
  float4 o = {a.x * sg + p.x * (1.f - sg), a.y * sg + p.y * (1.f - sg),
              a.z * sg + p.z * (1.f - sg), a.w * sg + p.w * (1.f - sg)};
  ((float4*)(out + (size_t)r * 512))[t] = o;
}

// ---------------------------------------------------------------------------
extern "C" void kernel_launch(void* const* d_in, const int* in_sizes, int n_in,
                              void* d_out, int out_size, void* d_ws, size_t ws_size,
                              hipStream_t stream) {
  const float* q    = (const float*)d_in[0];
  const float* prev = (const float*)d_in[1];
  const float* Wq   = (const float*)d_in[2];
  const float* bq   = (const float*)d_in[3];
  const float* Wk   = (const float*)d_in[4];
  const float* Wv   = (const float*)d_in[6];
  const float* bv   = (const float*)d_in[7];
  const float* Wg1  = (const float*)d_in[8];
  const float* bg1  = (const float*)d_in[9];
  const float* Wg2  = (const float*)d_in[10];
  const float* bg2  = (const float*)d_in[11];
  const float* dk   = (const float*)d_in[12];
  const float* dv   = (const float*)d_in[13];
  float* out = (float*)d_out;

  char* ws = (char*)d_ws;  // total 72,888,320 B (< 74.46 MB proven in r1-r3)
  u8*    kf8   = (u8*)(ws);                  // 16,777,216
  u8*    vtf8  = (u8*)(ws + 16777216);       // 16,777,216
  u16*   part  = (u16*)(ws + 33554432);      // 33,554,432
  float* racc  = (float*)(ws + 67108864);    // 2 MB
  float* lacc  = (float*)(ws + 69206016);    // 4 KB
  float* sdot  = (float*)(ws + 69210112);    // 4 KB (contiguous after lacc)
  u8*    q2f8  = (u8*)(ws + 69214208);       // 512 KB
  float* Wqk   = (float*)(ws + 69738496);    // 1 MB
  float* b2pre = (float*)(ws + 70787072);    // 4 KB
  float* attn  = (float*)(ws + 70791168);    // 2 MB

  // 1) preps: fp8 conversions, Wqk gemm, b2pre, lacc/sdot zero
  prep_all<<<8265, 256, 0, stream>>>(dk, dv, Wq, Wk, bq, kf8, vtf8, Wqk, b2pre,
                                     lacc);
  // 2) Q2f8 = fp8(16 * 2s * (q@Wqk + b2pre))
  gemm64<false, false, false, false, true, false, false, 512>
      <<<dim3(8, 16), 256, 0, stream>>>(q, nullptr, Wqk, b2pre, nullptr,
                                        nullptr, 1.4142135623730951f, q2f8,
                                        nullptr);
  // 3) flash attention over datastore (fp8 operands, bf16 partials)
  flash<<<512, 512, 0, stream>>>(kf8, vtf8, q2f8, part, lacc);
  // 4) racc = sum over chunks
  reduce_racc<<<1024, 256, 0, stream>>>(part, racc);
  // 5) attn = (racc/l) @ Wv^T + bv
  gemm64<false, true, false, false, false, true, false, 512>
      <<<dim3(8, 16), 256, 0, stream>>>(racc, nullptr, Wv, bv, lacc, nullptr,
                                        1.0f, attn, nullptr);
  // 6) sdot = relu([attn|prev]@Wg1^T + bg1).wg2
  gemm64<false, true, true, true, false, false, true, 1024>
      <<<dim3(8, 16), 256, 0, stream>>>(attn, prev, Wg1, bg1, nullptr, Wg2,
                                        1.0f, nullptr, sdot);
  // 7) gate + mix
  finalize<<<1024, 128, 0, stream>>>(sdot, bg2, attn, prev, out);
}